// Round 1
// baseline (1195.517 us; speedup 1.0000x reference)
//
#include <hip/hip_runtime.h>
#include <math.h>

#define B_    64
#define HW_   56
#define C_    128
#define WS_   7
#define SHIFT_ 3
#define NH_   4
#define DH_   32
#define NT_   49   // 7*7 tokens per window
#define NWS_  8    // windows per side

// LDS layout (float offsets)
#define OFF_X   0        // 49*128 = 6272  (reused as attn-out after phase 3)
#define OFF_Q   6272     // 4*49*32 = 6272
#define OFF_K   12544
#define OFF_V   18816
#define OFF_L   25088    // 4*49*49 = 9604 (logits)
#define OFF_REL 34692    // 169*4 = 676
#define SMEM_FLOATS 35368   // 141472 bytes

__global__ __launch_bounds__(256, 1)
void swin_fused(const float* __restrict__ x,
                const float* __restrict__ w_qkv,
                const float* __restrict__ b_qkv,
                const float* __restrict__ w_proj,
                const float* __restrict__ b_proj,
                const float* __restrict__ rel_table,
                float* __restrict__ out)
{
    extern __shared__ float sm[];
    const int tid = threadIdx.x;
    const int bn  = blockIdx.x;
    const int b   = bn >> 6;
    const int wi  = (bn >> 3) & 7;
    const int wj  = bn & 7;

    // ---------------- phase 1: load shifted window + rel_table ----------------
    // xs[h'] = x[(h'+SHIFT) % HW]  (roll by -SHIFT); same mapping used for store.
    for (int idx = tid; idx < NT_ * 32; idx += 256) {
        const int n  = idx >> 5;        // token 0..48
        const int c4 = idx & 31;        // float4 chunk 0..31
        const int i1 = n / 7, j1 = n % 7;
        int gh = wi * 7 + i1 + SHIFT_; if (gh >= HW_) gh -= HW_;
        int gw = wj * 7 + j1 + SHIFT_; if (gw >= HW_) gw -= HW_;
        const float4 v = *reinterpret_cast<const float4*>(
            x + (((size_t)b * HW_ + gh) * HW_ + gw) * C_ + c4 * 4);
        *reinterpret_cast<float4*>(&sm[OFF_X + n * C_ + c4 * 4]) = v;
    }
    for (int idx = tid; idx < 169 * NH_; idx += 256)
        sm[OFF_REL + idx] = rel_table[idx];
    __syncthreads();

    // ---------------- phase 2: QKV GEMM  [49x128] @ [128x384] ----------------
    // thread tile: 13 rows x 6 cols. 64 col-groups x 4 row-groups (row group == wave).
    {
        const int cs = tid & 63;
        const int rs = tid >> 6;
        const int c0 = cs * 6;
        const int r0 = rs * 13;

        float acc[13][6];
        float bia[6];
        #pragma unroll
        for (int j = 0; j < 6; ++j) bia[j] = b_qkv[c0 + j];
        #pragma unroll
        for (int r = 0; r < 13; ++r)
            #pragma unroll
            for (int j = 0; j < 6; ++j) acc[r][j] = bia[j];

        #pragma unroll 2
        for (int c = 0; c < C_; ++c) {
            const float* wr = w_qkv + c * 384 + c0;
            const float w0 = wr[0], w1 = wr[1], w2 = wr[2];
            const float w3 = wr[3], w4 = wr[4], w5 = wr[5];
            #pragma unroll
            for (int r = 0; r < 13; ++r) {
                // rows 49..51 read harmless garbage (inside LDS), stores skipped
                const float xv = sm[OFF_X + (r0 + r) * C_ + c];  // wave-uniform broadcast
                acc[r][0] += xv * w0; acc[r][1] += xv * w1; acc[r][2] += xv * w2;
                acc[r][3] += xv * w3; acc[r][4] += xv * w4; acc[r][5] += xv * w5;
            }
        }

        const float scale = 0.17677669529663687f;  // 1/sqrt(32)
        #pragma unroll
        for (int j = 0; j < 6; ++j) {
            const int cc    = c0 + j;
            const int which = cc >> 7;        // 0=q 1=k 2=v
            const int hd    = (cc >> 5) & 3;  // head
            const int dd    = cc & 31;        // dim
            const int base  = (which == 0 ? OFF_Q : (which == 1 ? OFF_K : OFF_V))
                              + hd * NT_ * DH_ + dd;
            const float mul = (which == 0) ? scale : 1.0f;
            #pragma unroll
            for (int r = 0; r < 13; ++r) {
                const int n = r0 + r;
                if (n < NT_) sm[base + n * DH_] = acc[r][j] * mul;
            }
        }
    }
    __syncthreads();

    // ---------------- phase 3: attention (one wave per head) ----------------
    {
        const int h = tid >> 6;    // head = wave id
        const int n = tid & 63;    // token row
        if (n < NT_) {
            const int i1 = n / 7, j1 = n % 7;
            const int hs  = wi * 7 + i1, ws2 = wj * 7 + j1;   // shifted coords
            const int rn  = (hs < 49 ? 0 : (hs < 53 ? 1 : 2)) * 3
                          + (ws2 < 49 ? 0 : (ws2 < 53 ? 1 : 2));

            float4 qr[8];
            #pragma unroll
            for (int j = 0; j < 8; ++j)
                qr[j] = *reinterpret_cast<const float4*>(
                    &sm[OFF_Q + h * NT_ * DH_ + n * DH_ + j * 4]);

            // pass 1: logits + row max
            float rowmax = -1e30f;
            for (int m = 0; m < NT_; ++m) {
                const float* kr = &sm[OFF_K + h * NT_ * DH_ + m * DH_];  // broadcast
                float dot = 0.f;
                #pragma unroll
                for (int j = 0; j < 8; ++j) {
                    const float4 kv = *reinterpret_cast<const float4*>(kr + j * 4);
                    dot += qr[j].x * kv.x + qr[j].y * kv.y
                         + qr[j].z * kv.z + qr[j].w * kv.w;
                }
                sm[OFF_L + (h * NT_ + n) * NT_ + m] = dot;
                rowmax = fmaxf(rowmax, dot);
            }
            // pass 1b: softmax denominator
            float ssum = 0.f;
            for (int m = 0; m < NT_; ++m)
                ssum += __expf(sm[OFF_L + (h * NT_ + n) * NT_ + m] - rowmax);
            const float rsum = 1.0f / ssum;

            // pass 2: attn = softmax + bias + mask (post-softmax, faithful), then @ V
            float4 o[8];
            #pragma unroll
            for (int j = 0; j < 8; ++j) { o[j].x = 0.f; o[j].y = 0.f; o[j].z = 0.f; o[j].w = 0.f; }

            for (int m = 0; m < NT_; ++m) {
                const int i2 = m / 7, j2 = m % 7;
                float a = __expf(sm[OFF_L + (h * NT_ + n) * NT_ + m] - rowmax) * rsum;
                a += sm[OFF_REL + ((i1 - i2 + 6) * 13 + (j1 - j2 + 6)) * NH_ + h];
                const int hs2 = wi * 7 + i2, ws3 = wj * 7 + j2;
                const int rm  = (hs2 < 49 ? 0 : (hs2 < 53 ? 1 : 2)) * 3
                              + (ws3 < 49 ? 0 : (ws3 < 53 ? 1 : 2));
                if (rm != rn) a -= 100.0f;

                const float* vr = &sm[OFF_V + h * NT_ * DH_ + m * DH_];  // broadcast
                #pragma unroll
                for (int j = 0; j < 8; ++j) {
                    const float4 vv = *reinterpret_cast<const float4*>(vr + j * 4);
                    o[j].x += a * vv.x; o[j].y += a * vv.y;
                    o[j].z += a * vv.z; o[j].w += a * vv.w;
                }
            }
            #pragma unroll
            for (int j = 0; j < 8; ++j)
                *reinterpret_cast<float4*>(&sm[OFF_X + n * C_ + h * DH_ + j * 4]) = o[j];
        }
    }
    __syncthreads();

    // ---------------- phase 4: proj GEMM [49x128] @ [128x128] + store ----------------
    {
        const int cs = tid & 63;
        const int rs = tid >> 6;
        const int c0 = cs * 2;
        const int r0 = rs * 13;

        float acc0[13], acc1[13];
        const float b0 = b_proj[c0], b1 = b_proj[c0 + 1];
        #pragma unroll
        for (int r = 0; r < 13; ++r) { acc0[r] = b0; acc1[r] = b1; }

        #pragma unroll 2
        for (int c = 0; c < C_; ++c) {
            const float w0 = w_proj[c * C_ + c0];
            const float w1 = w_proj[c * C_ + c0 + 1];
            #pragma unroll
            for (int r = 0; r < 13; ++r) {
                const float xv = sm[OFF_X + (r0 + r) * C_ + c];  // broadcast
                acc0[r] += xv * w0; acc1[r] += xv * w1;
            }
        }

        #pragma unroll
        for (int r = 0; r < 13; ++r) {
            const int n = r0 + r;
            if (n < NT_) {
                const int i1 = n / 7, j1 = n % 7;
                int gh = wi * 7 + i1 + SHIFT_; if (gh >= HW_) gh -= HW_;
                int gw = wj * 7 + j1 + SHIFT_; if (gw >= HW_) gw -= HW_;
                float2 res; res.x = acc0[r]; res.y = acc1[r];
                *reinterpret_cast<float2*>(
                    out + (((size_t)b * HW_ + gh) * HW_ + gw) * C_ + c0) = res;
            }
        }
    }
}

extern "C" void kernel_launch(void* const* d_in, const int* in_sizes, int n_in,
                              void* d_out, int out_size, void* d_ws, size_t ws_size,
                              hipStream_t stream) {
    const float* x      = (const float*)d_in[0];
    const float* w_qkv  = (const float*)d_in[1];
    const float* b_qkv  = (const float*)d_in[2];
    const float* w_proj = (const float*)d_in[3];
    const float* b_proj = (const float*)d_in[4];
    const float* rel    = (const float*)d_in[5];
    float* outp = (float*)d_out;

    // allow >64KB dynamic LDS (no-op if already allowed); not a stream op, capture-safe
    (void)hipFuncSetAttribute((const void*)swin_fused,
                              hipFuncAttributeMaxDynamicSharedMemorySize,
                              SMEM_FLOATS * 4);

    hipLaunchKernelGGL(swin_fused, dim3(64 * NWS_ * NWS_), dim3(256),
                       SMEM_FLOATS * 4, stream,
                       x, w_qkv, b_qkv, w_proj, b_proj, rel, outp);
}

// Round 2
// 142.626 us; speedup vs baseline: 8.3822x; 8.3822x over previous
//
#include <hip/hip_runtime.h>

#define B_     64
#define HW_    56
#define C_     128
#define SHIFT_ 3
#define NH_    4
#define NT_    49

typedef __attribute__((ext_vector_type(8))) __bf16 bf16x8;
typedef __attribute__((ext_vector_type(4))) float  f32x4;

// LDS byte-offset map (per block, 68240 B total):
//  X / X2 : [16 g][64 tok][16B]              @ 0      (16 KB)  swz 1024B groups
//  QK / P : per head h @ 16384+h*8192:
//           Q [4 g][64 tok][16B] (+0), K (+4096); P [8 g][64 q][16B] overlays
//  VT     : per head h @ 49152+h*4096: [8 g(tok)][32 d][16B]  swz 512B groups
//  rel    : f32[169][4] @ 65536 (2704 B)
#define XB    0
#define QKB   16384
#define VB    49152
#define RELB  65536
#define SMEMB 68240

__device__ __forceinline__ int swz(int g, int row) {          // 1024B-group regions
    return ((g << 10) + (row << 4)) ^ ((g & 7) << 4);
}
__device__ __forceinline__ int swzv(int g, int row) {         // 512B-group regions (VT)
    return ((g << 9) + (row << 4)) ^ ((g & 7) << 4);
}
__device__ __forceinline__ unsigned short f2bf(float f) {     // rte f32->bf16
    union { float f; unsigned u; } v; v.f = f;
    unsigned r = v.u + 0x7FFFu + ((v.u >> 16) & 1u);
    return (unsigned short)(r >> 16);
}
__device__ __forceinline__ int region(int c) { return c < 49 ? 0 : (c < 53 ? 1 : 2); }

// ---- prep: transpose + bf16-convert weights into d_ws ----
// ws[0..49151]        = wT  [384][128] : wT[oc][ic] = w_qkv[ic][oc]
// ws[49152..65535]    = wpT [128][128] : wpT[oc][ic] = w_proj[ic][oc]
__global__ void prep_weights(const float* __restrict__ wq, const float* __restrict__ wp,
                             unsigned short* __restrict__ ws) {
    int i = blockIdx.x * 256 + threadIdx.x;
    if (i < 49152) {
        int oc = i >> 7, ic = i & 127;
        ws[i] = f2bf(wq[ic * 384 + oc]);
    } else if (i < 65536) {
        int j = i - 49152;
        int oc = j >> 7, ic = j & 127;
        ws[i] = f2bf(wp[ic * 128 + oc]);
    }
}

__global__ __launch_bounds__(256, 2)
void swin_fused(const float* __restrict__ x,
                const float* __restrict__ b_qkv,
                const float* __restrict__ b_proj,
                const float* __restrict__ rel_table,
                const unsigned short* __restrict__ wsb,
                float* __restrict__ out)
{
    extern __shared__ char smc[];
    const __bf16* wt  = (const __bf16*)wsb;           // [384][128]
    const __bf16* wpt = (const __bf16*)(wsb + 49152); // [128][128]

    const int tid = threadIdx.x;
    const int bn  = blockIdx.x;
    const int b   = bn >> 6;
    const int wi  = (bn >> 3) & 7;
    const int wj  = bn & 7;

    const int w  = tid >> 6;        // wave id
    const int lr = tid & 15;        // lane % 16
    const int lg = (tid & 63) >> 4; // lane / 16

    // ---------------- phase 1: x -> X (bf16 frag-order), rel -> LDS ----------------
    {
        const int c8 = tid & 15;          // k-group (8 channels)
        const int t0 = tid >> 4;
        #pragma unroll
        for (int p = 0; p < 4; ++p) {
            const int tok = t0 + 16 * p;  // 0..63
            bf16x8* dst = (bf16x8*)(smc + XB + swz(c8, tok));
            if (tok < NT_) {
                const int i1 = tok / 7, j1 = tok - 7 * i1;
                int gh = wi * 7 + i1 + SHIFT_; if (gh >= HW_) gh -= HW_;
                int gw = wj * 7 + j1 + SHIFT_; if (gw >= HW_) gw -= HW_;
                const float* px = x + (((size_t)(b * HW_ + gh)) * HW_ + gw) * C_ + c8 * 8;
                float4 a0 = *(const float4*)(px);
                float4 a1 = *(const float4*)(px + 4);
                unsigned short u[8] = { f2bf(a0.x), f2bf(a0.y), f2bf(a0.z), f2bf(a0.w),
                                        f2bf(a1.x), f2bf(a1.y), f2bf(a1.z), f2bf(a1.w) };
                *dst = *(const bf16x8*)u;
            } else {
                unsigned short u[8] = {0,0,0,0,0,0,0,0};
                *dst = *(const bf16x8*)u;
            }
        }
        for (int i = tid; i < 169 * NH_; i += 256)
            ((float*)(smc + RELB))[i] = rel_table[i];
    }
    __syncthreads();

    // ---------------- phase 2: QKV' = Wt @ X^T  (M=384 oc, N=64 tok, K=128) ----------------
    {
        const int mtb = w * 6;
        f32x4 acc[6][4];
        #pragma unroll
        for (int i = 0; i < 6; ++i) {
            const int oc0 = (mtb + i) * 16 + lg * 4;
            f32x4 bv;
            #pragma unroll
            for (int r = 0; r < 4; ++r) bv[r] = b_qkv[oc0 + r];
            #pragma unroll
            for (int nt = 0; nt < 4; ++nt) acc[i][nt] = bv;
        }
        #pragma unroll 2
        for (int ks = 0; ks < 4; ++ks) {
            bf16x8 bfr[4];
            #pragma unroll
            for (int nt = 0; nt < 4; ++nt)
                bfr[nt] = *(const bf16x8*)(smc + XB + swz(ks * 4 + lg, nt * 16 + lr));
            #pragma unroll
            for (int i = 0; i < 6; ++i) {
                bf16x8 afr = *(const bf16x8*)(wt + ((mtb + i) * 16 + lr) * 128 + ks * 32 + lg * 8);
                #pragma unroll
                for (int nt = 0; nt < 4; ++nt)
                    acc[i][nt] = __builtin_amdgcn_mfma_f32_16x16x32_bf16(afr, bfr[nt], acc[i][nt], 0, 0, 0);
            }
        }
        // scatter C' rows (4 consecutive oc per lane) into Q/K (b64) and VT (b16)
        const float qscale = 0.17677669529663687f;
        #pragma unroll
        for (int i = 0; i < 6; ++i) {
            const int mt    = mtb + i;
            const int which = mt >> 3;        // 0=q 1=k 2=v
            const int hd    = (mt >> 1) & 3;
            const int d0    = ((mt & 1) << 4) + lg * 4;
            if (which < 2) {
                const float sc   = (which == 0) ? qscale : 1.0f;
                const int   base = QKB + hd * 8192 + which * 4096;
                const int   g = d0 >> 3, inner = (d0 & 4) << 1;
                #pragma unroll
                for (int nt = 0; nt < 4; ++nt) {
                    const int tok = nt * 16 + lr;
                    short4 pk;
                    pk.x = (short)f2bf(acc[i][nt][0] * sc);
                    pk.y = (short)f2bf(acc[i][nt][1] * sc);
                    pk.z = (short)f2bf(acc[i][nt][2] * sc);
                    pk.w = (short)f2bf(acc[i][nt][3] * sc);
                    *(short4*)(smc + base + swz(g, tok) + inner) = pk;
                }
            } else {
                const int vb = VB + hd * 4096;
                #pragma unroll
                for (int nt = 0; nt < 4; ++nt) {
                    const int tok = nt * 16 + lr;
                    #pragma unroll
                    for (int r = 0; r < 4; ++r)
                        *(short*)(smc + vb + swzv(tok >> 3, d0 + r) + ((tok & 7) << 1)) =
                            (short)f2bf(acc[i][nt][r]);
                }
            }
        }
    }
    __syncthreads();

    // ---------------- phase 3: attention, wave = head ----------------
    {
        const int h   = w;
        const int qb_ = QKB + h * 8192;
        const int kb_ = qb_ + 4096;
        const int vb_ = VB + h * 4096;
        const float* relf = (const float*)(smc + RELB);

        // S^T = K @ Q^T  (M=64 keys, N=64 q, K=32)
        bf16x8 ka[4], qf[4];
        #pragma unroll
        for (int mt = 0; mt < 4; ++mt)
            ka[mt] = *(const bf16x8*)(smc + kb_ + swz(lg, mt * 16 + lr));
        #pragma unroll
        for (int nt = 0; nt < 4; ++nt)
            qf[nt] = *(const bf16x8*)(smc + qb_ + swz(lg, nt * 16 + lr));
        f32x4 s[4][4];
        #pragma unroll
        for (int mt = 0; mt < 4; ++mt)
            #pragma unroll
            for (int nt = 0; nt < 4; ++nt) {
                f32x4 z = {0.f, 0.f, 0.f, 0.f};
                s[mt][nt] = __builtin_amdgcn_mfma_f32_16x16x32_bf16(ka[mt], qf[nt], z, 0, 0, 0);
            }

        // per-lane key coords: m = mt*16 + lg*4 + r
        int i2a[16], j2a[16], rma[16];
        #pragma unroll
        for (int mt = 0; mt < 4; ++mt)
            #pragma unroll
            for (int r = 0; r < 4; ++r) {
                int m = mt * 16 + lg * 4 + r; if (m >= NT_) m = 0;   // clamp (unused when invalid)
                const int i2 = m / 7, j2 = m - 7 * i2;
                i2a[mt * 4 + r] = i2; j2a[mt * 4 + r] = j2;
                rma[mt * 4 + r] = region(wi * 7 + i2) * 3 + region(wj * 7 + j2);
            }

        // softmax (over keys) + post-softmax bias & mask -> P (bf16 in LDS, overlays Q/K)
        #pragma unroll
        for (int nt = 0; nt < 4; ++nt) {
            float mx = -3.0e38f;
            #pragma unroll
            for (int mt = 0; mt < 3; ++mt)
                #pragma unroll
                for (int r = 0; r < 4; ++r) mx = fmaxf(mx, s[mt][nt][r]);
            if (lg == 0) mx = fmaxf(mx, s[3][nt][0]);
            mx = fmaxf(mx, __shfl_xor(mx, 16));
            mx = fmaxf(mx, __shfl_xor(mx, 32));
            float sum = 0.f;
            #pragma unroll
            for (int mt = 0; mt < 3; ++mt)
                #pragma unroll
                for (int r = 0; r < 4; ++r) {
                    const float e = __expf(s[mt][nt][r] - mx);
                    s[mt][nt][r] = e; sum += e;
                }
            {
                const float e = (lg == 0) ? __expf(s[3][nt][0] - mx) : 0.f;
                s[3][nt][0] = e; s[3][nt][1] = 0.f; s[3][nt][2] = 0.f; s[3][nt][3] = 0.f;
                sum += e;
            }
            sum += __shfl_xor(sum, 16);
            sum += __shfl_xor(sum, 32);
            const float rs = 1.0f / sum;

            const int q  = nt * 16 + lr;
            const int qc = (q < NT_) ? q : 48;
            const int i1 = qc / 7, j1 = qc - 7 * i1;
            const int rn = region(wi * 7 + i1) * 3 + region(wj * 7 + j1);

            #pragma unroll
            for (int mt = 0; mt < 4; ++mt) {
                unsigned short pk[4];
                #pragma unroll
                for (int r = 0; r < 4; ++r) {
                    const bool valid = (mt < 3) || (lg == 0 && r == 0);
                    const int  idx = mt * 4 + r;
                    float p = s[mt][nt][r] * rs
                            + relf[((i1 - i2a[idx] + 6) * 13 + (j1 - j2a[idx] + 6)) * NH_ + h]
                            + ((rma[idx] != rn) ? -100.0f : 0.0f);
                    pk[r] = valid ? f2bf(p) : (unsigned short)0;
                }
                const int m0 = mt * 16 + lg * 4;
                short4 v4; v4.x = (short)pk[0]; v4.y = (short)pk[1];
                           v4.z = (short)pk[2]; v4.w = (short)pk[3];
                *(short4*)(smc + qb_ + swz(m0 >> 3, q) + ((m0 & 4) << 1)) = v4;
            }
        }

        // O^T = VT @ P^T  (M=32 d, N=64 q, K=64 keys) -> X2 (overlays X)
        f32x4 o[2][4];
        #pragma unroll
        for (int mt = 0; mt < 2; ++mt)
            #pragma unroll
            for (int nt = 0; nt < 4; ++nt) { f32x4 z = {0.f,0.f,0.f,0.f}; o[mt][nt] = z; }
        #pragma unroll
        for (int ks = 0; ks < 2; ++ks) {
            bf16x8 va[2], pf[4];
            #pragma unroll
            for (int mt = 0; mt < 2; ++mt)
                va[mt] = *(const bf16x8*)(smc + vb_ + swzv(ks * 4 + lg, mt * 16 + lr));
            #pragma unroll
            for (int nt = 0; nt < 4; ++nt)
                pf[nt] = *(const bf16x8*)(smc + qb_ + swz(ks * 4 + lg, nt * 16 + lr));
            #pragma unroll
            for (int mt = 0; mt < 2; ++mt)
                #pragma unroll
                for (int nt = 0; nt < 4; ++nt)
                    o[mt][nt] = __builtin_amdgcn_mfma_f32_16x16x32_bf16(va[mt], pf[nt], o[mt][nt], 0, 0, 0);
        }
        #pragma unroll
        for (int mt = 0; mt < 2; ++mt) {
            const int c0 = h * 32 + mt * 16 + lg * 4;
            const int g = c0 >> 3, inner = (c0 & 4) << 1;
            #pragma unroll
            for (int nt = 0; nt < 4; ++nt) {
                short4 pk;
                pk.x = (short)f2bf(o[mt][nt][0]); pk.y = (short)f2bf(o[mt][nt][1]);
                pk.z = (short)f2bf(o[mt][nt][2]); pk.w = (short)f2bf(o[mt][nt][3]);
                *(short4*)(smc + XB + swz(g, nt * 16 + lr) + inner) = pk;
            }
        }
    }
    __syncthreads();

    // ---------------- phase 4: proj = X2 @ Wp  (M=64 tok, N=128 oc, K=128) + store ----------------
    {
        f32x4 pacc[4][2];
        #pragma unroll
        for (int ntl = 0; ntl < 2; ++ntl) {
            const float bv = b_proj[(w * 2 + ntl) * 16 + lr];
            #pragma unroll
            for (int mt = 0; mt < 4; ++mt) {
                f32x4 v = {bv, bv, bv, bv};
                pacc[mt][ntl] = v;
            }
        }
        #pragma unroll 2
        for (int ks = 0; ks < 4; ++ks) {
            bf16x8 af[4], bfp[2];
            #pragma unroll
            for (int mt = 0; mt < 4; ++mt)
                af[mt] = *(const bf16x8*)(smc + XB + swz(ks * 4 + lg, mt * 16 + lr));
            #pragma unroll
            for (int ntl = 0; ntl < 2; ++ntl)
                bfp[ntl] = *(const bf16x8*)(wpt + ((w * 2 + ntl) * 16 + lr) * 128 + ks * 32 + lg * 8);
            #pragma unroll
            for (int mt = 0; mt < 4; ++mt)
                #pragma unroll
                for (int ntl = 0; ntl < 2; ++ntl)
                    pacc[mt][ntl] = __builtin_amdgcn_mfma_f32_16x16x32_bf16(af[mt], bfp[ntl], pacc[mt][ntl], 0, 0, 0);
        }
        #pragma unroll
        for (int mt = 0; mt < 4; ++mt)
            #pragma unroll
            for (int r = 0; r < 4; ++r) {
                const int tok = mt * 16 + lg * 4 + r;
                if (tok < NT_) {
                    const int i1 = tok / 7, j1 = tok - 7 * i1;
                    int gh = wi * 7 + i1 + SHIFT_; if (gh >= HW_) gh -= HW_;
                    int gw = wj * 7 + j1 + SHIFT_; if (gw >= HW_) gw -= HW_;
                    float* po = out + (((size_t)(b * HW_ + gh)) * HW_ + gw) * C_;
                    #pragma unroll
                    for (int ntl = 0; ntl < 2; ++ntl)
                        po[(w * 2 + ntl) * 16 + lr] = pacc[mt][ntl][r];
                }
            }
    }
}

extern "C" void kernel_launch(void* const* d_in, const int* in_sizes, int n_in,
                              void* d_out, int out_size, void* d_ws, size_t ws_size,
                              hipStream_t stream) {
    const float* x      = (const float*)d_in[0];
    const float* w_qkv  = (const float*)d_in[1];
    const float* b_qkv  = (const float*)d_in[2];
    const float* w_proj = (const float*)d_in[3];
    const float* b_proj = (const float*)d_in[4];
    const float* rel    = (const float*)d_in[5];
    float* outp = (float*)d_out;
    unsigned short* wsb = (unsigned short*)d_ws;

    (void)hipFuncSetAttribute((const void*)swin_fused,
                              hipFuncAttributeMaxDynamicSharedMemorySize, SMEMB);

    hipLaunchKernelGGL(prep_weights, dim3(256), dim3(256), 0, stream, w_qkv, w_proj, wsb);
    hipLaunchKernelGGL(swin_fused, dim3(4096), dim3(256), SMEMB, stream,
                       x, b_qkv, b_proj, rel, wsb, outp);
}

// Round 3
// 121.739 us; speedup vs baseline: 9.8204x; 1.1716x over previous
//
#include <hip/hip_runtime.h>

#define HW_    56
#define C_     128
#define SHIFT_ 3
#define NH_    4
#define NT_    49

typedef __attribute__((ext_vector_type(8))) __bf16 bf16x8;
typedef __attribute__((ext_vector_type(4))) float  f32x4;

// d_ws layout:
//   shorts [0, 65536)      : wT[384][128] (oc-major) then wpT[128][128]
//   bytes  [131072, +3.2MB): f32 cb[wpos=64][h=4][q=49][k=64]  (bias + mask, post-softmax)
#define WS_CB_BYTE  131072
#define CB_ELEMS    (64 * 4 * 49 * 64)

// LDS (49152 B, 3 blocks/CU):
//   XB  (16KB): X bf16 frag-order [16 g][64 tok][16B]; after phase 2 reused as
//               V^T per head h at XB+h*4096: [8 g(tok)][32 d][16B]
//   QKB (32KB): per head h at QKB+h*8192: Q(+0, 4KB), K(+4096, 4KB);
//               P overlays Q after softmax; X2 (attn out) overlays K after PV
#define XB    0
#define QKB   16384
#define SMEMB 49152

__device__ __forceinline__ int swz(int g, int row) {          // 1024B-row-group regions
    return ((g << 10) + (row << 4)) ^ ((g & 7) << 4);
}
__device__ __forceinline__ int swzv(int g, int row) {         // 512B-row-group regions (VT)
    return ((g << 9) + (row << 4)) ^ ((g & 7) << 4);
}
__device__ __forceinline__ int x2addr(int g, int tok) {       // X2 over K sub-regions
    return QKB + (g >> 2) * 8192 + 4096 + (g & 3) * 1024 + ((tok << 4) ^ ((g & 7) << 4));
}
__device__ __forceinline__ unsigned short bfbits(float f) {   // native cast -> v_cvt_pk
    __bf16 h = (__bf16)f;
    union { __bf16 b; unsigned short u; } c; c.b = h; return c.u;
}
__device__ __forceinline__ int region(int c) { return c < 49 ? 0 : (c < 53 ? 1 : 2); }

// ---- prep 1: transpose + bf16-convert weights ----
__global__ void prep_weights(const float* __restrict__ wq, const float* __restrict__ wp,
                             unsigned short* __restrict__ ws) {
    int i = blockIdx.x * 256 + threadIdx.x;
    if (i < 49152) {
        int oc = i >> 7, ic = i & 127;
        ws[i] = bfbits(wq[ic * 384 + oc]);
    } else if (i < 65536) {
        int j = i - 49152;
        int oc = j >> 7, ic = j & 127;
        ws[i] = bfbits(wp[ic * 128 + oc]);
    }
}

// ---- prep 2: combined post-softmax bias + shifted-window mask ----
__global__ void prep_bias(const float* __restrict__ rel_table, float* __restrict__ cb) {
    int i = blockIdx.x * 256 + threadIdx.x;
    if (i >= CB_ELEMS) return;
    int k = i & 63;
    int t = i >> 6;          // (wpos*4 + h)*49 + q
    int q = t % 49;
    int u = t / 49;
    int h = u & 3;
    int wpos = u >> 2;
    float v = 0.f;
    if (k < 49) {
        int iq = q / 7, jq = q - 7 * iq;
        int ik = k / 7, jk = k - 7 * ik;
        int wi = wpos >> 3, wj = wpos & 7;
        v = rel_table[((iq - ik + 6) * 13 + (jq - jk + 6)) * NH_ + h];
        int rq = region(wi * 7 + iq) * 3 + region(wj * 7 + jq);
        int rk = region(wi * 7 + ik) * 3 + region(wj * 7 + jk);
        if (rq != rk) v -= 100.0f;
    }
    cb[i] = v;
}

__global__ __launch_bounds__(256, 3)
void swin_fused(const float* __restrict__ x,
                const float* __restrict__ b_qkv,
                const float* __restrict__ b_proj,
                const unsigned short* __restrict__ wsb,
                const float* __restrict__ cb,
                float* __restrict__ out)
{
    extern __shared__ char smc[];
    const __bf16* wt  = (const __bf16*)wsb;           // [384][128]
    const __bf16* wpt = (const __bf16*)(wsb + 49152); // [128][128]

    const int tid = threadIdx.x;
    const int bn  = blockIdx.x;
    const int b   = bn >> 6;
    const int wi  = (bn >> 3) & 7;
    const int wj  = bn & 7;

    const int w  = tid >> 6;        // wave id
    const int lr = tid & 15;        // lane % 16
    const int lg = (tid & 63) >> 4; // lane / 16

    // ---------------- phase 1: x -> X (bf16 frag-order) ----------------
    {
        const int c8 = tid & 15;          // k-group (8 channels)
        const int t0 = tid >> 4;
        #pragma unroll
        for (int p = 0; p < 4; ++p) {
            const int tok = t0 + 16 * p;  // 0..63
            bf16x8* dst = (bf16x8*)(smc + XB + swz(c8, tok));
            union { bf16x8 v; __bf16 e[8]; } u;
            if (tok < NT_) {
                const int i1 = tok / 7, j1 = tok - 7 * i1;
                int gh = wi * 7 + i1 + SHIFT_; if (gh >= HW_) gh -= HW_;
                int gw = wj * 7 + j1 + SHIFT_; if (gw >= HW_) gw -= HW_;
                const float* px = x + (((size_t)(b * HW_ + gh)) * HW_ + gw) * C_ + c8 * 8;
                float4 a0 = *(const float4*)(px);
                float4 a1 = *(const float4*)(px + 4);
                u.e[0] = (__bf16)a0.x; u.e[1] = (__bf16)a0.y;
                u.e[2] = (__bf16)a0.z; u.e[3] = (__bf16)a0.w;
                u.e[4] = (__bf16)a1.x; u.e[5] = (__bf16)a1.y;
                u.e[6] = (__bf16)a1.z; u.e[7] = (__bf16)a1.w;
            } else {
                #pragma unroll
                for (int e = 0; e < 8; ++e) u.e[e] = (__bf16)0.0f;
            }
            *dst = u.v;
        }
    }
    __syncthreads();

    // ---------------- phase 2: QKV' = Wt @ X^T  (M=384 oc, N=64 tok, K=128) ----------------
    // col blocks per wave: mt = w + 4*i  ->  i<4: 2 q + 2 k cols; i in {4,5}: 2 v cols
    f32x4 acc[6][4];
    {
        #pragma unroll
        for (int i = 0; i < 6; ++i) {
            const int oc0 = (w + 4 * i) * 16 + lg * 4;
            f32x4 bv;
            #pragma unroll
            for (int r = 0; r < 4; ++r) bv[r] = b_qkv[oc0 + r];
            #pragma unroll
            for (int nt = 0; nt < 4; ++nt) acc[i][nt] = bv;
        }
        #pragma unroll 2
        for (int ks = 0; ks < 4; ++ks) {
            bf16x8 bfr[4];
            #pragma unroll
            for (int nt = 0; nt < 4; ++nt)
                bfr[nt] = *(const bf16x8*)(smc + XB + swz(ks * 4 + lg, nt * 16 + lr));
            #pragma unroll
            for (int i = 0; i < 6; ++i) {
                const int mt = w + 4 * i;
                bf16x8 afr = *(const bf16x8*)(wt + (mt * 16 + lr) * 128 + ks * 32 + lg * 8);
                #pragma unroll
                for (int nt = 0; nt < 4; ++nt)
                    acc[i][nt] = __builtin_amdgcn_mfma_f32_16x16x32_bf16(afr, bfr[nt], acc[i][nt], 0, 0, 0);
            }
        }
        // scatter q/k cols into Q/K regions (b64 stores)
        const float qscale = 0.17677669529663687f;
        #pragma unroll
        for (int i = 0; i < 4; ++i) {
            const int mt    = w + 4 * i;
            const int which = mt >> 3;        // 0=q 1=k
            const int hd    = (mt >> 1) & 3;
            const int d0    = ((mt & 1) << 4) + lg * 4;
            const float sc  = (which == 0) ? qscale : 1.0f;
            const int base  = QKB + hd * 8192 + which * 4096;
            const int g = d0 >> 3, inner = (d0 & 4) << 1;
            #pragma unroll
            for (int nt = 0; nt < 4; ++nt) {
                const int tok = nt * 16 + lr;
                union { short4 s4; __bf16 e[4]; } pk;
                #pragma unroll
                for (int r = 0; r < 4; ++r) pk.e[r] = (__bf16)(acc[i][nt][r] * sc);
                *(short4*)(smc + base + swz(g, tok) + inner) = pk.s4;
            }
        }
    }
    __syncthreads();
    // V scatter into the now-dead X region (V^T per head)
    {
        #pragma unroll
        for (int i = 4; i < 6; ++i) {
            const int mt = w + 4 * i;
            const int hd = (mt >> 1) & 3;
            const int d0 = ((mt & 1) << 4) + lg * 4;
            const int vb2 = XB + hd * 4096;
            #pragma unroll
            for (int nt = 0; nt < 4; ++nt) {
                const int tok = nt * 16 + lr;
                #pragma unroll
                for (int r = 0; r < 4; ++r)
                    *(unsigned short*)(smc + vb2 + swzv(tok >> 3, d0 + r) + ((tok & 7) << 1)) =
                        bfbits(acc[i][nt][r]);
            }
        }
    }
    __syncthreads();

    // ---------------- phase 3: attention, wave = head ----------------
    {
        const int h   = w;
        const int qb_ = QKB + h * 8192;
        const int kb_ = qb_ + 4096;
        const int vb_ = XB + h * 4096;
        const float* cbw = cb + (((size_t)(wi * 8 + wj) * 4 + h) * 49) * 64;

        // S^T = K @ Q^T  (M=64 keys, N=64 q, K=32)
        bf16x8 ka[4], qf[4];
        #pragma unroll
        for (int mt = 0; mt < 4; ++mt)
            ka[mt] = *(const bf16x8*)(smc + kb_ + swz(lg, mt * 16 + lr));
        #pragma unroll
        for (int nt = 0; nt < 4; ++nt)
            qf[nt] = *(const bf16x8*)(smc + qb_ + swz(lg, nt * 16 + lr));
        f32x4 s[4][4];
        #pragma unroll
        for (int mt = 0; mt < 4; ++mt)
            #pragma unroll
            for (int nt = 0; nt < 4; ++nt) {
                f32x4 z = {0.f, 0.f, 0.f, 0.f};
                s[mt][nt] = __builtin_amdgcn_mfma_f32_16x16x32_bf16(ka[mt], qf[nt], z, 0, 0, 0);
            }

        // softmax over keys + post-softmax (bias+mask) from cb -> P (bf16, overlays Q)
        #pragma unroll
        for (int nt = 0; nt < 4; ++nt) {
            float mx = -3.0e38f;
            #pragma unroll
            for (int mt = 0; mt < 3; ++mt)
                #pragma unroll
                for (int r = 0; r < 4; ++r) mx = fmaxf(mx, s[mt][nt][r]);
            if (lg == 0) mx = fmaxf(mx, s[3][nt][0]);
            mx = fmaxf(mx, __shfl_xor(mx, 16));
            mx = fmaxf(mx, __shfl_xor(mx, 32));
            float sum = 0.f;
            #pragma unroll
            for (int mt = 0; mt < 3; ++mt)
                #pragma unroll
                for (int r = 0; r < 4; ++r) {
                    const float e = __expf(s[mt][nt][r] - mx);
                    s[mt][nt][r] = e; sum += e;
                }
            {
                const float e = (lg == 0) ? __expf(s[3][nt][0] - mx) : 0.f;
                s[3][nt][0] = e;
                sum += e;
            }
            sum += __shfl_xor(sum, 16);
            sum += __shfl_xor(sum, 32);
            const float rs = 1.0f / sum;

            const int q  = nt * 16 + lr;
            const int qc = (q < NT_) ? q : 48;
            const float* cbq = cbw + qc * 64;

            #pragma unroll
            for (int mt = 0; mt < 4; ++mt) {
                const f32x4 bv = *(const f32x4*)(cbq + mt * 16 + lg * 4);
                union { short4 s4; __bf16 e[4]; } pk;
                #pragma unroll
                for (int r = 0; r < 4; ++r) {
                    const bool valid = (mt < 3) || (lg == 0 && r == 0);
                    const float p = fmaf(s[mt][nt][r], rs, bv[r]);
                    pk.e[r] = valid ? (__bf16)p : (__bf16)0.0f;
                }
                const int m0 = mt * 16 + lg * 4;
                *(short4*)(smc + qb_ + swz(m0 >> 3, q) + ((m0 & 4) << 1)) = pk.s4;
            }
        }

        // O^T = VT @ P^T  (M=32 d, N=64 q, K=64 keys) -> X2 (overlays own head's K)
        f32x4 o[2][4];
        #pragma unroll
        for (int mt = 0; mt < 2; ++mt)
            #pragma unroll
            for (int nt = 0; nt < 4; ++nt) { f32x4 z = {0.f,0.f,0.f,0.f}; o[mt][nt] = z; }
        #pragma unroll
        for (int ks = 0; ks < 2; ++ks) {
            bf16x8 va[2], pf[4];
            #pragma unroll
            for (int mt = 0; mt < 2; ++mt)
                va[mt] = *(const bf16x8*)(smc + vb_ + swzv(ks * 4 + lg, mt * 16 + lr));
            #pragma unroll
            for (int nt = 0; nt < 4; ++nt)
                pf[nt] = *(const bf16x8*)(smc + qb_ + swz(ks * 4 + lg, nt * 16 + lr));
            #pragma unroll
            for (int mt = 0; mt < 2; ++mt)
                #pragma unroll
                for (int nt = 0; nt < 4; ++nt)
                    o[mt][nt] = __builtin_amdgcn_mfma_f32_16x16x32_bf16(va[mt], pf[nt], o[mt][nt], 0, 0, 0);
        }
        #pragma unroll
        for (int mt = 0; mt < 2; ++mt) {
            const int c0 = h * 32 + mt * 16 + lg * 4;
            const int g = c0 >> 3, inner = (c0 & 4) << 1;
            #pragma unroll
            for (int nt = 0; nt < 4; ++nt) {
                union { short4 s4; __bf16 e[4]; } pk;
                #pragma unroll
                for (int r = 0; r < 4; ++r) pk.e[r] = (__bf16)o[mt][nt][r];
                *(short4*)(smc + x2addr(g, nt * 16 + lr) + inner) = pk.s4;
            }
        }
    }
    __syncthreads();

    // ---------------- phase 4: proj = X2 @ Wp  (M=64 tok, N=128 oc, K=128) + store ----------------
    {
        f32x4 pacc[4][2];
        #pragma unroll
        for (int ntl = 0; ntl < 2; ++ntl) {
            const float bv = b_proj[(w * 2 + ntl) * 16 + lr];
            #pragma unroll
            for (int mt = 0; mt < 4; ++mt) {
                f32x4 v = {bv, bv, bv, bv};
                pacc[mt][ntl] = v;
            }
        }
        #pragma unroll 2
        for (int ks = 0; ks < 4; ++ks) {
            bf16x8 af[4], bfp[2];
            #pragma unroll
            for (int mt = 0; mt < 4; ++mt)
                af[mt] = *(const bf16x8*)(smc + x2addr(ks * 4 + lg, mt * 16 + lr));
            #pragma unroll
            for (int ntl = 0; ntl < 2; ++ntl)
                bfp[ntl] = *(const bf16x8*)(wpt + ((w * 2 + ntl) * 16 + lr) * 128 + ks * 32 + lg * 8);
            #pragma unroll
            for (int mt = 0; mt < 4; ++mt)
                #pragma unroll
                for (int ntl = 0; ntl < 2; ++ntl)
                    pacc[mt][ntl] = __builtin_amdgcn_mfma_f32_16x16x32_bf16(af[mt], bfp[ntl], pacc[mt][ntl], 0, 0, 0);
        }
        #pragma unroll
        for (int mt = 0; mt < 4; ++mt)
            #pragma unroll
            for (int r = 0; r < 4; ++r) {
                const int tok = mt * 16 + lg * 4 + r;
                if (tok < NT_) {
                    const int i1 = tok / 7, j1 = tok - 7 * i1;
                    int gh = wi * 7 + i1 + SHIFT_; if (gh >= HW_) gh -= HW_;
                    int gw = wj * 7 + j1 + SHIFT_; if (gw >= HW_) gw -= HW_;
                    float* po = out + (((size_t)(b * HW_ + gh)) * HW_ + gw) * C_;
                    #pragma unroll
                    for (int ntl = 0; ntl < 2; ++ntl)
                        po[(w * 2 + ntl) * 16 + lr] = pacc[mt][ntl][r];
                }
            }
    }
}

extern "C" void kernel_launch(void* const* d_in, const int* in_sizes, int n_in,
                              void* d_out, int out_size, void* d_ws, size_t ws_size,
                              hipStream_t stream) {
    const float* x      = (const float*)d_in[0];
    const float* w_qkv  = (const float*)d_in[1];
    const float* b_qkv  = (const float*)d_in[2];
    const float* w_proj = (const float*)d_in[3];
    const float* b_proj = (const float*)d_in[4];
    const float* rel    = (const float*)d_in[5];
    float* outp = (float*)d_out;
    unsigned short* wsb = (unsigned short*)d_ws;
    float* cbp = (float*)((char*)d_ws + WS_CB_BYTE);

    hipLaunchKernelGGL(prep_weights, dim3(256), dim3(256), 0, stream, w_qkv, w_proj, wsb);
    hipLaunchKernelGGL(prep_bias, dim3((CB_ELEMS + 255) / 256), dim3(256), 0, stream, rel, cbp);
    hipLaunchKernelGGL(swin_fused, dim3(4096), dim3(256), SMEMB, stream,
                       x, b_qkv, b_proj, wsb, cbp, outp);
}